// Round 1
// baseline (135.685 us; speedup 1.0000x reference)
//
#include <hip/hip_runtime.h>

// Problem constants (from reference)
#define B_DIM 16384
#define IN_FEATURES 8192
#define OUT_FEATURES 1024
#define BLOCK_SIZE 8               // IN_FEATURES / OUT_FEATURES
#define N_OUT (B_DIM * OUT_FEATURES)   // 16,777,216 output elements

// Kernel 1: w[i] = exp(log_weight[i]) for the 8192-entry table -> d_ws
__global__ void blocklinear_expw_kernel(const float* __restrict__ lw,
                                        float* __restrict__ w) {
    int i = blockIdx.x * blockDim.x + threadIdx.x;
    if (i < OUT_FEATURES * BLOCK_SIZE) {
        w[i] = expf(lw[i]);
    }
}

// Kernel 2: y[b, o] = sum_k w[o,k] * x[b, o*8 + k]
// One thread per output element; grid-stride. x read as 2x float4 (32B/lane,
// coalesced: consecutive threads own consecutive 32B chunks). Weight table is
// 32 KiB -> L1/L2 resident.
__global__ void blocklinear_main_kernel(const float* __restrict__ x,
                                        const float* __restrict__ w,
                                        float* __restrict__ y) {
    const size_t total = (size_t)N_OUT;
    const size_t stride = (size_t)gridDim.x * blockDim.x;
    for (size_t i = (size_t)blockIdx.x * blockDim.x + threadIdx.x;
         i < total; i += stride) {
        const int o = (int)(i & (OUT_FEATURES - 1));
        const float4* xp = (const float4*)(x + i * BLOCK_SIZE);
        const float4* wp = (const float4*)(w + (size_t)o * BLOCK_SIZE);
        float4 x0 = xp[0];
        float4 x1 = xp[1];
        float4 w0 = wp[0];
        float4 w1 = wp[1];
        float s = x0.x * w0.x + x0.y * w0.y + x0.z * w0.z + x0.w * w0.w
                + x1.x * w1.x + x1.y * w1.y + x1.z * w1.z + x1.w * w1.w;
        y[i] = s;
    }
}

extern "C" void kernel_launch(void* const* d_in, const int* in_sizes, int n_in,
                              void* d_out, int out_size, void* d_ws, size_t ws_size,
                              hipStream_t stream) {
    const float* x = (const float*)d_in[0];          // [B, IN_FEATURES] f32
    const float* log_weight = (const float*)d_in[1]; // [OUT_FEATURES, BLOCK_SIZE] f32
    float* y = (float*)d_out;                        // [B, OUT_FEATURES] f32
    float* w_exp = (float*)d_ws;                     // 8192 floats = 32 KiB scratch

    // Precompute exp(log_weight) -> workspace (deterministic each call).
    blocklinear_expw_kernel<<<(OUT_FEATURES * BLOCK_SIZE + 255) / 256, 256, 0, stream>>>(
        log_weight, w_exp);

    // Main memory-bound pass.
    const int block = 256;
    const int grid = 2048;  // ~8 blocks/CU, grid-stride covers 16.7M outputs
    blocklinear_main_kernel<<<grid, block, 0, stream>>>(x, w_exp, y);
}

// Round 2
// 133.916 us; speedup vs baseline: 1.0132x; 1.0132x over previous
//
#include <hip/hip_runtime.h>

// Problem constants (from reference)
#define B_DIM 16384
#define IN_FEATURES 8192
#define OUT_FEATURES 1024
#define BLOCK_SIZE 8                     // IN_FEATURES / OUT_FEATURES
#define N_OUT (B_DIM * OUT_FEATURES)     // 16,777,216 output elements

#define GRID 2048
#define BLOCK 256
#define STRIDE (GRID * BLOCK)            // 524288 threads
#define N_ITERS (N_OUT / STRIDE)         // 32 outputs per thread (exact)

// Fused kernel: y[b, o] = sum_k exp(lw[o,k]) * x[b, o*8 + k]
//
// Key facts exploited:
//  - STRIDE % OUT_FEATURES == 0, so each thread's output column o is
//    LOOP-INVARIANT: load its 8 log-weights and compute the 8 exps ONCE,
//    amortized over 32 output elements. Inner loop is then pure streaming:
//    2x global_load_dwordx4 (32 B/lane, coalesced) + 8 fma + 1 store.
//  - Weight table is 32 KiB -> L1-resident for the one-time load.
__global__ __launch_bounds__(BLOCK) void blocklinear_fused_kernel(
        const float* __restrict__ x,
        const float* __restrict__ lw,
        float* __restrict__ y) {
    const int t = blockIdx.x * BLOCK + threadIdx.x;   // [0, STRIDE)
    const int o = t & (OUT_FEATURES - 1);             // invariant across iters

    // One-time: load 8 log-weights (2x float4, cached) and exponentiate.
    const float4* lwp = (const float4*)(lw + (size_t)o * BLOCK_SIZE);
    const float4 l0 = lwp[0];
    const float4 l1 = lwp[1];
    const float w0 = expf(l0.x), w1 = expf(l0.y), w2 = expf(l0.z), w3 = expf(l0.w);
    const float w4 = expf(l1.x), w5 = expf(l1.y), w6 = expf(l1.z), w7 = expf(l1.w);

    size_t i = (size_t)t;
    #pragma unroll 4
    for (int it = 0; it < N_ITERS; ++it, i += STRIDE) {
        const float4* xp = (const float4*)(x + i * (size_t)BLOCK_SIZE);
        const float4 x0 = xp[0];
        const float4 x1 = xp[1];
        const float s = x0.x * w0 + x0.y * w1 + x0.z * w2 + x0.w * w3
                      + x1.x * w4 + x1.y * w5 + x1.z * w6 + x1.w * w7;
        y[i] = s;
    }
}

extern "C" void kernel_launch(void* const* d_in, const int* in_sizes, int n_in,
                              void* d_out, int out_size, void* d_ws, size_t ws_size,
                              hipStream_t stream) {
    const float* x = (const float*)d_in[0];          // [B, IN_FEATURES] f32
    const float* log_weight = (const float*)d_in[1]; // [OUT_FEATURES, 8] f32
    float* y = (float*)d_out;                        // [B, OUT_FEATURES] f32

    blocklinear_fused_kernel<<<GRID, BLOCK, 0, stream>>>(x, log_weight, y);
}

// Round 3
// 125.111 us; speedup vs baseline: 1.0845x; 1.0704x over previous
//
#include <hip/hip_runtime.h>

// Problem constants (from reference)
#define B_DIM 16384
#define IN_FEATURES 8192
#define OUT_FEATURES 1024
#define BLOCK_SIZE 8                     // IN_FEATURES / OUT_FEATURES
#define N_OUT (B_DIM * OUT_FEATURES)     // 16,777,216 outputs
#define N_F4 (B_DIM * IN_FEATURES / 4)   // 33,554,432 float4s of x

#define GRID 2048
#define BLOCK 256
#define NWAVES (GRID * BLOCK / 64)       // 8192 waves
#define STEP_F4 (NWAVES * 128)           // 1,048,576 f4 consumed per step (mult of 2048)
#define OUT_PER_STEP (NWAVES * 64)       // 524,288 outputs per step
#define N_STEPS (N_F4 / STEP_F4)         // 32, exact

// Wave-cooperative layout: per step a wave consumes 128 contiguous float4s of x
// (2048 B) via TWO fully lane-contiguous global_load_dwordx4 (1024 B/instr),
// producing 64 outputs. float4 #g belongs to output g>>1 (k-half g&1), and its
// weight float4 index is g&2047 — loop-invariant per lane since STEP_F4 is a
// multiple of 2048. Lane pairs combine halves with one __shfl_xor; even lanes
// store 2x 128B-contiguous runs.
__global__ __launch_bounds__(BLOCK) void blocklinear_coop_kernel(
        const float* __restrict__ x,
        const float* __restrict__ lw,
        float* __restrict__ y) {
    const int tid  = blockIdx.x * BLOCK + threadIdx.x;
    const int lane = threadIdx.x & 63;
    const int wave = tid >> 6;                 // global wave id [0, NWAVES)

    const float4* x4  = (const float4*)x;
    const float4* lw4 = (const float4*)lw;    // 2048 float4s = 32 KiB, L1-resident

    // Loop-invariant weight fragments for this lane (one-time exp).
    const int wi0 = (wave * 128 + lane) & 2047;   // wi0+64 never wraps (<=2047)
    const float4 la = lw4[wi0];
    const float4 lb = lw4[wi0 + 64];
    const float4 wa = make_float4(expf(la.x), expf(la.y), expf(la.z), expf(la.w));
    const float4 wb = make_float4(expf(lb.x), expf(lb.y), expf(lb.z), expf(lb.w));

    size_t base = (size_t)wave * 128;          // f4 index of this wave's chunk
    int    ob   = wave * 64;                   // output index base
    const bool storer = ((lane & 1) == 0);
    const int  m = lane >> 1;

    #pragma unroll 4
    for (int s = 0; s < N_STEPS; ++s) {
        const float4 xa = x4[base + lane];        // contiguous 1024 B across wave
        const float4 xb = x4[base + 64 + lane];   // contiguous 1024 B across wave
        const float pa = xa.x*wa.x + xa.y*wa.y + xa.z*wa.z + xa.w*wa.w;
        const float pb = xb.x*wb.x + xb.y*wb.y + xb.z*wb.z + xb.w*wb.w;
        const float sa = pa + __shfl_xor(pa, 1, 64);  // pair-sum: full output
        const float sb = pb + __shfl_xor(pb, 1, 64);
        if (storer) {                              // even lanes: 2x 128B contiguous
            y[ob + m]      = sa;
            y[ob + 32 + m] = sb;
        }
        base += STEP_F4;
        ob   += OUT_PER_STEP;
    }
}

extern "C" void kernel_launch(void* const* d_in, const int* in_sizes, int n_in,
                              void* d_out, int out_size, void* d_ws, size_t ws_size,
                              hipStream_t stream) {
    const float* x = (const float*)d_in[0];          // [B, IN_FEATURES] f32
    const float* log_weight = (const float*)d_in[1]; // [OUT_FEATURES, 8] f32
    float* y = (float*)d_out;                        // [B, OUT_FEATURES] f32

    blocklinear_coop_kernel<<<GRID, BLOCK, 0, stream>>>(x, log_weight, y);
}

// Round 5
// 110.352 us; speedup vs baseline: 1.2296x; 1.1337x over previous
//
#include <hip/hip_runtime.h>

// Problem constants (from reference)
#define B_DIM 16384
#define IN_FEATURES 8192
#define OUT_FEATURES 1024
#define BLOCK_SIZE 8                     // IN_FEATURES / OUT_FEATURES
#define N_OUT (B_DIM * OUT_FEATURES)     // 16,777,216 outputs
#define N_F4 (B_DIM * IN_FEATURES / 4)   // 33,554,432 float4s of x

#define GRID 2048
#define BLOCK 256
#define NWAVES (GRID * BLOCK / 64)       // 8192 waves (= 32 waves/CU, max occ)
#define F4_PER_WAVE_STEP 256             // 4 KiB per wave per step (4 loads)
#define STEP_F4 (NWAVES * F4_PER_WAVE_STEP)   // 2,097,152 f4/step (mult of 2048)
#define OUT_PER_STEP (STEP_F4 / 2)       // 1,048,576 outputs/step
#define N_STEPS (N_F4 / STEP_F4)         // 16, exact

// Native clang vector type — __builtin_nontemporal_load/store accept these
// (they reject HIP_vector_type structs).
typedef float f32x4 __attribute__((ext_vector_type(4)));

// Wave-cooperative streaming kernel with nontemporal hints.
// Per step, a wave reads 256 contiguous float4s of x (4 KiB) via FOUR fully
// lane-contiguous nontemporal global_load_dwordx4 (1024 B each), issued
// back-to-back for MLP. float4 #g maps to output g>>1 (k-half g&1); weight f4
// index g&2047 is loop-invariant per lane (STEP_F4 % 2048 == 0), so exp runs
// once. Lane pairs combine halves with one __shfl_xor each; even lanes issue
// four 128B-contiguous nontemporal stores.
__global__ __launch_bounds__(BLOCK) void blocklinear_nt_kernel(
        const float* __restrict__ x,
        const float* __restrict__ lw,
        float* __restrict__ y) {
    const int tid  = blockIdx.x * BLOCK + threadIdx.x;
    const int lane = threadIdx.x & 63;
    const int wave = tid >> 6;                 // global wave id [0, NWAVES)

    const f32x4* x4  = (const f32x4*)x;
    const f32x4* lw4 = (const f32x4*)lw;      // 2048 float4s = 32 KiB, cached

    // Loop-invariant weight fragments (one-time exp). No wrap within a step:
    // (wave*256 mod 2048) + 192 + 63 <= 2047.
    const int wi0 = (wave * F4_PER_WAVE_STEP + lane) & 2047;
    const f32x4 l0 = lw4[wi0];
    const f32x4 l1 = lw4[wi0 + 64];
    const f32x4 l2 = lw4[wi0 + 128];
    const f32x4 l3 = lw4[wi0 + 192];
    f32x4 w0_, w1_, w2_, w3_;
    w0_.x = expf(l0.x); w0_.y = expf(l0.y); w0_.z = expf(l0.z); w0_.w = expf(l0.w);
    w1_.x = expf(l1.x); w1_.y = expf(l1.y); w1_.z = expf(l1.z); w1_.w = expf(l1.w);
    w2_.x = expf(l2.x); w2_.y = expf(l2.y); w2_.z = expf(l2.z); w2_.w = expf(l2.w);
    w3_.x = expf(l3.x); w3_.y = expf(l3.y); w3_.z = expf(l3.z); w3_.w = expf(l3.w);

    size_t base = (size_t)wave * F4_PER_WAVE_STEP;  // f4 index of wave's chunk
    int    ob   = wave * (F4_PER_WAVE_STEP / 2);    // output index base
    const bool storer = ((lane & 1) == 0);
    const int  m = lane >> 1;                       // [0,32)

    #pragma unroll 2
    for (int s = 0; s < N_STEPS; ++s) {
        // Issue all four wave-contiguous loads before consuming any.
        const f32x4 xa = __builtin_nontemporal_load(&x4[base + lane]);
        const f32x4 xb = __builtin_nontemporal_load(&x4[base + 64 + lane]);
        const f32x4 xc = __builtin_nontemporal_load(&x4[base + 128 + lane]);
        const f32x4 xd = __builtin_nontemporal_load(&x4[base + 192 + lane]);

        const float pa = xa.x*w0_.x + xa.y*w0_.y + xa.z*w0_.z + xa.w*w0_.w;
        const float pb = xb.x*w1_.x + xb.y*w1_.y + xb.z*w1_.z + xb.w*w1_.w;
        const float pc = xc.x*w2_.x + xc.y*w2_.y + xc.z*w2_.z + xc.w*w2_.w;
        const float pd = xd.x*w3_.x + xd.y*w3_.y + xd.z*w3_.z + xd.w*w3_.w;

        const float sa = pa + __shfl_xor(pa, 1, 64);
        const float sb = pb + __shfl_xor(pb, 1, 64);
        const float sc = pc + __shfl_xor(pc, 1, 64);
        const float sd = pd + __shfl_xor(pd, 1, 64);

        if (storer) {   // even lanes: four 128B-contiguous nontemporal stores
            __builtin_nontemporal_store(sa, &y[ob + m]);
            __builtin_nontemporal_store(sb, &y[ob + 32 + m]);
            __builtin_nontemporal_store(sc, &y[ob + 64 + m]);
            __builtin_nontemporal_store(sd, &y[ob + 96 + m]);
        }
        base += STEP_F4;
        ob   += OUT_PER_STEP;
    }
}

extern "C" void kernel_launch(void* const* d_in, const int* in_sizes, int n_in,
                              void* d_out, int out_size, void* d_ws, size_t ws_size,
                              hipStream_t stream) {
    const float* x = (const float*)d_in[0];          // [B, IN_FEATURES] f32
    const float* log_weight = (const float*)d_in[1]; // [OUT_FEATURES, 8] f32
    float* y = (float*)d_out;                        // [B, OUT_FEATURES] f32

    blocklinear_nt_kernel<<<GRID, BLOCK, 0, stream>>>(x, log_weight, y);
}

// Round 6
// 106.612 us; speedup vs baseline: 1.2727x; 1.0351x over previous
//
#include <hip/hip_runtime.h>

// Problem constants (from reference)
#define B_DIM 16384
#define IN_FEATURES 8192
#define OUT_FEATURES 1024
#define BLOCK_SIZE 8                     // IN_FEATURES / OUT_FEATURES
#define N_OUT (B_DIM * OUT_FEATURES)     // 16,777,216 outputs
#define N_F4 (B_DIM * IN_FEATURES / 4)   // 33,554,432 float4s of x

#define GRID 2048
#define BLOCK 256
#define NWAVES (GRID * BLOCK / 64)       // 8192 waves (= 32 waves/CU, max occ)
#define F4_PER_WAVE_STEP 512             // 8 KiB per wave per step (8 loads)
#define STEP_F4 (NWAVES * F4_PER_WAVE_STEP)   // 4,194,304 f4/step (mult of 2048)
#define OUT_PER_STEP (STEP_F4 / 2)
#define N_STEPS (N_F4 / STEP_F4)         // 8, exact

// Native clang vector type — __builtin_nontemporal_load/store accept these.
typedef float f32x4 __attribute__((ext_vector_type(4)));

// Wave-cooperative streaming kernel, 8-deep load batching + nontemporal.
// Per step a wave reads 512 contiguous float4s of x (8 KiB) via EIGHT fully
// lane-contiguous nontemporal global_load_dwordx4 (1024 B each), all issued
// before any consumption (max memory-level parallelism). float4 #g maps to
// output g>>1 (k-half g&1); weight f4 index g&2047 is loop-invariant per lane
// (STEP_F4 % 2048 == 0; window check: (wave*512 mod 2048) + 448 + 63 <= 2047,
// no wrap), so the 32 exps run once. Lane pairs combine halves with one
// __shfl_xor; even lanes issue 128B-contiguous nontemporal stores.
__global__ __launch_bounds__(BLOCK) void blocklinear_nt8_kernel(
        const float* __restrict__ x,
        const float* __restrict__ lw,
        float* __restrict__ y) {
    const int tid  = blockIdx.x * BLOCK + threadIdx.x;
    const int lane = threadIdx.x & 63;
    const int wave = tid >> 6;                 // global wave id [0, NWAVES)

    const f32x4* x4  = (const f32x4*)x;
    const f32x4* lw4 = (const f32x4*)lw;      // 2048 f4 = 32 KiB, cache-resident

    // Loop-invariant weight fragments (one-time exp), 8 float4s per lane.
    const int wi0 = (wave * F4_PER_WAVE_STEP + lane) & 2047;
    f32x4 w[8];
    #pragma unroll
    for (int j = 0; j < 8; ++j) {
        const f32x4 l = lw4[wi0 + j * 64];
        w[j].x = expf(l.x); w[j].y = expf(l.y);
        w[j].z = expf(l.z); w[j].w = expf(l.w);
    }

    size_t base = (size_t)wave * F4_PER_WAVE_STEP;  // f4 index of wave's chunk
    int    ob   = wave * (F4_PER_WAVE_STEP / 2);    // output index base
    const bool storer = ((lane & 1) == 0);
    const int  m = lane >> 1;                       // [0,32)

    #pragma unroll
    for (int s = 0; s < N_STEPS; ++s) {
        // Issue all eight wave-contiguous loads before consuming any.
        f32x4 xv[8];
        #pragma unroll
        for (int j = 0; j < 8; ++j)
            xv[j] = __builtin_nontemporal_load(&x4[base + j * 64 + lane]);

        float sv[8];
        #pragma unroll
        for (int j = 0; j < 8; ++j) {
            const float p = xv[j].x * w[j].x + xv[j].y * w[j].y
                          + xv[j].z * w[j].z + xv[j].w * w[j].w;
            sv[j] = p + __shfl_xor(p, 1, 64);     // pair-sum: full output
        }

        if (storer) {   // even lanes: eight 128B-contiguous nontemporal stores
            #pragma unroll
            for (int j = 0; j < 8; ++j)
                __builtin_nontemporal_store(sv[j], &y[ob + j * 32 + m]);
        }
        base += STEP_F4;
        ob   += OUT_PER_STEP;
    }
}

extern "C" void kernel_launch(void* const* d_in, const int* in_sizes, int n_in,
                              void* d_out, int out_size, void* d_ws, size_t ws_size,
                              hipStream_t stream) {
    const float* x = (const float*)d_in[0];          // [B, IN_FEATURES] f32
    const float* log_weight = (const float*)d_in[1]; // [OUT_FEATURES, 8] f32
    float* y = (float*)d_out;                        // [B, OUT_FEATURES] f32

    blocklinear_nt8_kernel<<<GRID, BLOCK, 0, stream>>>(x, log_weight, y);
}